// Round 13
// baseline (322.647 us; speedup 1.0000x reference)
//
#include <hip/hip_runtime.h>
#include <math.h>

// Problem constants (B=2, C=64, inter=32, H=W=80 -> N=6400)
#define BATCH 2
#define CH    64
#define INTER 32
#define NPOS  6400
#define LOG2E 1.44269504088896f
#define SPLIT 10          // key-dim split factor
#define TPB   5           // 128-key tiles per split chunk (5*128*10 = 6400)
#define NQB   (NPOS / 64) // 100 query tiles of 64

typedef _Float16 f16x8 __attribute__((ext_vector_type(8)));  // MFMA A/B frag
typedef _Float16 f16x2 __attribute__((ext_vector_type(2)));
typedef _Float16 h4    __attribute__((ext_vector_type(4)));
typedef float    f32x4 __attribute__((ext_vector_type(4)));  // MFMA C/D

// v_cvt_pkrtz returns __fp16x2; bit-identical to _Float16x2 -> bit_cast.
static __device__ __forceinline__ f16x2 pkrtz(float a, float b) {
    return __builtin_bit_cast(f16x2, __builtin_amdgcn_cvt_pkrtz(a, b));
}

// ---------------------------------------------------------------------------
// Kernel 1: projections -> fp16 workspace (+ zero the split counters).
// Grid (N/64, 3, B); blockIdx.y:
//   0: theta -> Qh [b][n][32], scaled by log2(e)
//   1: phi   -> Kh [b][n][32]
//   2: g     -> Vt [b][32][N] with per-128-tile SLOT PERMUTATION:
//      key kk -> slot (g>>1)*32 + qd*8 + (g&1)*4 + rr  (g=kk>>4,
//      qd=(kk>>2)&3, rr=kk&3) so the flash kernel's register-resident P^T
//      lines up with V's A-fragment slots. (Ref-verified R7/R10.)
// ---------------------------------------------------------------------------
__global__ __launch_bounds__(256) void nlb_proj_kernel(
    const float* __restrict__ x,
    const float* __restrict__ g_w,
    const float* __restrict__ th_w,
    const float* __restrict__ ph_w,
    _Float16* __restrict__ Qh, _Float16* __restrict__ Kh,
    _Float16* __restrict__ Vt, int* __restrict__ cnt)
{
    const int b  = blockIdx.z;
    const int p  = blockIdx.y;
    const int n0 = blockIdx.x * 64;
    const int t  = threadIdx.x;
    const int w  = __builtin_amdgcn_readfirstlane(t) >> 6;  // wave id (uniform)
    const int lane = t & 63;

    // zero split counters (ws is poisoned 0xAA before every launch);
    // runs before the flash kernel by stream order.
    if (p == 0 && t == 0) cnt[b * NQB + blockIdx.x] = 0;

    const float* wsrc = (p == 0) ? th_w : (p == 1) ? ph_w : g_w;
    const float* xg = x + (size_t)b * CH * NPOS + n0 + lane;

    float xr[64];
    #pragma unroll
    for (int c = 0; c < 64; c++) xr[c] = xg[(size_t)c * NPOS];

    __shared__ float buf[32][65];

    float accs[8];
    #pragma unroll
    for (int rr = 0; rr < 8; rr++) {
        const int row = w * 8 + rr;                  // wave-uniform
        const float* wr = wsrc + row * 64;           // -> scalar loads
        float a0 = 0.f, a1 = 0.f, a2 = 0.f, a3 = 0.f;
        #pragma unroll
        for (int c = 0; c < 16; c++) {
            a0 += wr[c]      * xr[c];
            a1 += wr[c + 16] * xr[c + 16];
            a2 += wr[c + 32] * xr[c + 32];
            a3 += wr[c + 48] * xr[c + 48];
        }
        accs[rr] = (a0 + a1) + (a2 + a3);
    }

    if (p == 2) {   // V^T with per-tile slot permutation
        const int n   = n0 + lane;
        const int kk  = n & 127;
        const int g   = kk >> 4, qd = (kk >> 2) & 3, rr2 = kk & 3;
        const int slot = (g >> 1) * 32 + qd * 8 + (g & 1) * 4 + rr2;
        const size_t col = (size_t)(n >> 7) * 128 + slot;
        #pragma unroll
        for (int rr = 0; rr < 8; rr++)
            Vt[((size_t)b * 32 + w * 8 + rr) * NPOS + col] = (_Float16)accs[rr];
        return;
    }

    #pragma unroll
    for (int rr = 0; rr < 8; rr++) buf[w * 8 + rr][lane] = accs[rr];
    __syncthreads();

    const float scale = (p == 0) ? LOG2E : 1.f;
    _Float16* dst = (p == 0) ? Qh : Kh;
    const int pos = t >> 2, ic = t & 3;   // 8 consecutive inter-ch per thread
    f16x8 hv;
    #pragma unroll
    for (int j = 0; j < 8; j++)
        hv[j] = (_Float16)(buf[ic * 8 + j][pos] * scale);
    *(f16x8*)(dst + ((size_t)b * NPOS + n0 + pos) * 32 + ic * 8) = hv;
}

// LDS overlay: flash staging (38 KB) and combine tail (20 KB) never live
// simultaneously (separated by __syncthreads + fence).
struct SmemFlash {
    _Float16 ks[2][128][40];   // 80B rows
    _Float16 vs[2][32][136];   // 272B rows
};
struct SmemTail {
    float wf[64][33];
    float wts[64][12];
    float of[64][33];
};

// ---------------------------------------------------------------------------
// Kernel 2: fp16 MFMA flash attention, split-K (R10 structure, verbatim
// K-loop: register-P transposed dataflow + double-buffered LDS, one barrier
// per tile) + FUSED split-K combine: the last of the 10 split-blocks per
// (q-tile, b) — detected via device-scope atomicAdd with release/acquire
// threadfences (G16 cross-XCD) — merges the partials, applies W-projection
// + residual, stores the final output. No separate combine dispatch.
// ---------------------------------------------------------------------------
__global__ __launch_bounds__(256) void nlb_flash_kernel(
    const _Float16* __restrict__ Qh, const _Float16* __restrict__ Kh,
    const _Float16* __restrict__ Vt,
    _Float16* __restrict__ Opart, float2* __restrict__ ml,
    int* __restrict__ cnt,
    const float* __restrict__ w_w, const float* __restrict__ x,
    float* __restrict__ out)
{
    constexpr size_t SMEM_BYTES =
        sizeof(SmemFlash) > sizeof(SmemTail) ? sizeof(SmemFlash) : sizeof(SmemTail);
    __shared__ __align__(16) char smem[SMEM_BYTES];
    __shared__ int lastFlag;
    SmemFlash* sf = (SmemFlash*)smem;

    const int b     = blockIdx.z;
    const int split = blockIdx.y;
    const int t     = threadIdx.x;
    const int w     = t >> 6;
    const int lane  = t & 63;
    const int n16   = lane & 15;
    const int quad  = lane >> 4;
    const int q0    = blockIdx.x * 64 + w * 16;

    // Q fragment (B-operand of Q^T)
    const f16x8 qa = *(const f16x8*)(Qh + ((size_t)b * NPOS + q0 + n16) * 32 + quad * 8);

    const _Float16* KB = Kh + (size_t)b * NPOS * 32;
    const _Float16* VB = Vt + (size_t)b * 32 * NPOS;

    f32x4 o0 = (f32x4)0.f;              // dims quad*4+r      (query n16)
    f32x4 o1 = (f32x4)0.f;              // dims 16+quad*4+r
    float runm = -1e30f, lsum = 0.f;    // per-lane state for query n16

    // staging address components (two 16B chunks per thread for K and V)
    const int key0 = t >> 2, part = t & 3, key1 = key0 + 64;
    const int dim0 = t >> 4, kp   = t & 15, dim1 = dim0 + 16;

    const int kt0 = split * TPB;
    f16x8 kr0, kr1, vr0, vr1;
    {   // prologue fetch of first tile
        const int k0 = kt0 * 128;
        kr0 = *(const f16x8*)(KB + (size_t)(k0 + key0) * 32 + part * 8);
        kr1 = *(const f16x8*)(KB + (size_t)(k0 + key1) * 32 + part * 8);
        vr0 = *(const f16x8*)(VB + (size_t)dim0 * NPOS + k0 + kp * 8);
        vr1 = *(const f16x8*)(VB + (size_t)dim1 * NPOS + k0 + kp * 8);
    }

    for (int i = 0; i < TPB; i++) {
        const int cur = i & 1;
        *(f16x8*)&sf->ks[cur][key0][part * 8] = kr0;
        *(f16x8*)&sf->ks[cur][key1][part * 8] = kr1;
        *(f16x8*)&sf->vs[cur][dim0][kp * 8]   = vr0;
        *(f16x8*)&sf->vs[cur][dim1][kp * 8]   = vr1;
        __syncthreads();   // the ONLY barrier per tile (dbuf)

        if (i + 1 < TPB) {   // next-tile globals; in flight through compute
            const int k0n = (kt0 + i + 1) * 128;
            kr0 = *(const f16x8*)(KB + (size_t)(k0n + key0) * 32 + part * 8);
            kr1 = *(const f16x8*)(KB + (size_t)(k0n + key1) * 32 + part * 8);
            vr0 = *(const f16x8*)(VB + (size_t)dim0 * NPOS + k0n + kp * 8);
            vr1 = *(const f16x8*)(VB + (size_t)dim1 * NPOS + k0n + kp * 8);
        }

        // S^T = K Q^T
        f32x4 sc[8];
        #pragma unroll
        for (int g = 0; g < 8; g++) {
            f16x8 kf = *(const f16x8*)&sf->ks[cur][g * 16 + n16][quad * 8];
            f32x4 z = (f32x4)0.f;
            sc[g] = __builtin_amdgcn_mfma_f32_16x16x32_f16(kf, qa, z, 0, 0, 0);
        }

        // softmax over this query's 128 keys (lane owns 32; rest in n16+16k)
        float m = fmaxf(fmaxf(sc[0][0], sc[0][1]), fmaxf(sc[0][2], sc[0][3]));
        #pragma unroll
        for (int g = 1; g < 8; g++) {
            float mg = fmaxf(fmaxf(sc[g][0], sc[g][1]), fmaxf(sc[g][2], sc[g][3]));
            m = fmaxf(m, mg);
        }
        m = fmaxf(m, __shfl_xor(m, 16));
        m = fmaxf(m, __shfl_xor(m, 32));
        float nm = fmaxf(runm, m);
        float a  = __builtin_amdgcn_exp2f(runm - nm);
        runm = nm;
        float ls = 0.f;
        #pragma unroll
        for (int g = 0; g < 8; g++) {
            #pragma unroll
            for (int r = 0; r < 4; r++) {
                float p = __builtin_amdgcn_exp2f(sc[g][r] - nm);
                sc[g][r] = p;
                ls += p;
            }
        }
        lsum = lsum * a + ls;   // cross-quad sum deferred to epilogue
        o0 *= a;
        o1 *= a;

        // O^T += V^T P^T : pb[j] = P[key (kc*2+(j>>2))*16+quad*4+(j&3)]
        #pragma unroll
        for (int kc = 0; kc < 4; kc++) {
            union { f16x8 v; f16x2 h2[4]; } pb;
            pb.h2[0] = pkrtz(sc[kc * 2][0],     sc[kc * 2][1]);
            pb.h2[1] = pkrtz(sc[kc * 2][2],     sc[kc * 2][3]);
            pb.h2[2] = pkrtz(sc[kc * 2 + 1][0], sc[kc * 2 + 1][1]);
            pb.h2[3] = pkrtz(sc[kc * 2 + 1][2], sc[kc * 2 + 1][3]);
            f16x8 v0 = *(const f16x8*)&sf->vs[cur][n16][kc * 32 + quad * 8];
            f16x8 v1 = *(const f16x8*)&sf->vs[cur][16 + n16][kc * 32 + quad * 8];
            o0 = __builtin_amdgcn_mfma_f32_16x16x32_f16(v0, pb.v, o0, 0, 0, 0);
            o1 = __builtin_amdgcn_mfma_f32_16x16x32_f16(v1, pb.v, o1, 0, 0, 0);
        }
    }

    // epilogue: finish l across quads, normalize, store O^T + (m,l)
    lsum += __shfl_xor(lsum, 16);
    lsum += __shfl_xor(lsum, 32);
    float invl = 1.f / lsum;
    const size_t base = ((size_t)(b * SPLIT + split) * NPOS + q0 + n16) * 32;
    h4 h0, h1;
    #pragma unroll
    for (int r = 0; r < 4; r++) {
        h0[r] = (_Float16)(o0[r] * invl);
        h1[r] = (_Float16)(o1[r] * invl);
    }
    *(h4*)(Opart + base + quad * 4)      = h0;
    *(h4*)(Opart + base + 16 + quad * 4) = h1;
    if (quad == 0)
        ml[(size_t)(b * SPLIT + split) * NPOS + q0 + n16] = make_float2(runm, lsum);

    // ---- fused split-K combine: last block per (q-tile, b) wins ----
    __threadfence();          // release: publish Opart/ml device-wide
    __syncthreads();          // all threads' stores + fences done
    if (t == 0) {
        int old = atomicAdd(&cnt[b * NQB + blockIdx.x], 1);  // device scope
        lastFlag = (old == SPLIT - 1);
    }
    __syncthreads();
    if (!lastFlag) return;
    __threadfence();          // acquire: see other blocks' Opart/ml

    SmemTail* st = (SmemTail*)smem;    // staging buffers are dead now
    const int q0b = blockIdx.x * 64;

    for (int idx = t; idx < 2048; idx += 256)
        st->wf[idx >> 5][idx & 31] = w_w[idx];

    if (t < 64) {   // merge coefficients c_s = exp2(m_s-m*)*l_s / sum
        float2 v[SPLIT];
        float m = -1e30f;
        #pragma unroll
        for (int s = 0; s < SPLIT; s++) {
            v[s] = ml[(size_t)(b * SPLIT + s) * NPOS + q0b + t];
            m = fmaxf(m, v[s].x);
        }
        float suml = 0.f;
        #pragma unroll
        for (int s = 0; s < SPLIT; s++) {
            float wgt = __builtin_amdgcn_exp2f(v[s].x - m) * v[s].y;
            st->wts[t][s] = wgt;
            suml += wgt;
        }
        float inv = 1.f / suml;
        #pragma unroll
        for (int s = 0; s < SPLIT; s++) st->wts[t][s] *= inv;
    }
    __syncthreads();

    {   // merge partial O: thread -> (q = t>>2, dims dg*8..dg*8+7) COALESCED
        const int q = t >> 2, dg = t & 3;
        float acc[8];
        #pragma unroll
        for (int d = 0; d < 8; d++) acc[d] = 0.f;
        #pragma unroll
        for (int s = 0; s < SPLIT; s++) {
            f16x8 hv = *(const f16x8*)(Opart +
                ((size_t)(b * SPLIT + s) * NPOS + q0b + q) * 32 + dg * 8);
            float c = st->wts[q][s];
            #pragma unroll
            for (int d = 0; d < 8; d++) acc[d] += c * (float)hv[d];
        }
        #pragma unroll
        for (int d = 0; d < 8; d++) st->of[q][dg * 8 + d] = acc[d];
    }
    __syncthreads();

    {   // y = W o + x: thread -> (q = t&63, channels cg*16..+15)
        const int q = t & 63, cg = t >> 6;
        const float* xb = x   + (size_t)b * CH * NPOS + q0b + q;
        float*       ob = out + (size_t)b * CH * NPOS + q0b + q;
        #pragma unroll
        for (int cc = 0; cc < 16; cc++) {
            int ch = cg * 16 + cc;
            float acc = 0.f;
            #pragma unroll
            for (int i = 0; i < 32; i++) acc += st->wf[ch][i] * st->of[q][i];
            ob[(size_t)ch * NPOS] = acc + xb[(size_t)ch * NPOS];
        }
    }
}

extern "C" void kernel_launch(void* const* d_in, const int* in_sizes, int n_in,
                              void* d_out, int out_size, void* d_ws, size_t ws_size,
                              hipStream_t stream) {
    const float* x    = (const float*)d_in[0];
    const float* g_w  = (const float*)d_in[1];
    const float* th_w = (const float*)d_in[2];
    const float* ph_w = (const float*)d_in[3];
    const float* w_w  = (const float*)d_in[4];
    float* out = (float*)d_out;

    const size_t SZ = (size_t)BATCH * NPOS * INTER;   // 409600 elements
    _Float16* Qh = (_Float16*)d_ws;
    _Float16* Kh = Qh + SZ;
    _Float16* Vt = Kh + SZ;
    _Float16* Opart = Vt + SZ;                         // [B][SPLIT][N][32]
    float2*   ml    = (float2*)(Opart + SZ * SPLIT);   // [B][SPLIT][N]
    int*      cnt   = (int*)(ml + (size_t)BATCH * SPLIT * NPOS);  // [B][NQB]

    nlb_proj_kernel<<<dim3(NPOS / 64, 3, BATCH), 256, 0, stream>>>(
        x, g_w, th_w, ph_w, Qh, Kh, Vt, cnt);
    nlb_flash_kernel<<<dim3(NQB, SPLIT, BATCH), 256, 0, stream>>>(
        Qh, Kh, Vt, Opart, ml, cnt, w_w, x, out);
}

// Round 14
// 106.849 us; speedup vs baseline: 3.0196x; 3.0196x over previous
//
#include <hip/hip_runtime.h>
#include <math.h>

// Problem constants (B=2, C=64, inter=32, H=W=80 -> N=6400)
#define BATCH 2
#define CH    64
#define INTER 32
#define NPOS  6400
#define LOG2E 1.44269504088896f
#define SPLIT 10          // key-dim split factor
#define TPB   5           // 128-key tiles per split chunk (5*128*10 = 6400)

typedef _Float16 f16x8 __attribute__((ext_vector_type(8)));  // MFMA A/B frag
typedef _Float16 f16x2 __attribute__((ext_vector_type(2)));
typedef _Float16 h4    __attribute__((ext_vector_type(4)));
typedef float    f32x4 __attribute__((ext_vector_type(4)));  // MFMA C/D

// v_cvt_pkrtz returns __fp16x2; bit-identical to _Float16x2 -> bit_cast.
static __device__ __forceinline__ f16x2 pkrtz(float a, float b) {
    return __builtin_bit_cast(f16x2, __builtin_amdgcn_cvt_pkrtz(a, b));
}

// ---------------------------------------------------------------------------
// Kernel 1: projections -> fp16 workspace. Grid (N/64, 3, B); blockIdx.y:
//   0: theta -> Qh [b][n][32], scaled by log2(e)
//   1: phi   -> Kh [b][n][32]
//   2: g     -> Vt [b][32][N] with per-128-tile SLOT PERMUTATION:
//      key kk -> slot (g>>1)*32 + qd*8 + (g&1)*4 + rr  (g=kk>>4,
//      qd=(kk>>2)&3, rr=kk&3) so the flash kernel's register-resident P^T
//      lines up with V's A-fragment slots. (Ref-verified R7/R10/R12.)
// ---------------------------------------------------------------------------
__global__ __launch_bounds__(256) void nlb_proj_kernel(
    const float* __restrict__ x,
    const float* __restrict__ g_w,
    const float* __restrict__ th_w,
    const float* __restrict__ ph_w,
    _Float16* __restrict__ Qh, _Float16* __restrict__ Kh,
    _Float16* __restrict__ Vt)
{
    const int b  = blockIdx.z;
    const int p  = blockIdx.y;
    const int n0 = blockIdx.x * 64;
    const int t  = threadIdx.x;
    const int w  = __builtin_amdgcn_readfirstlane(t) >> 6;  // wave id (uniform)
    const int lane = t & 63;

    const float* wsrc = (p == 0) ? th_w : (p == 1) ? ph_w : g_w;
    const float* xg = x + (size_t)b * CH * NPOS + n0 + lane;

    float xr[64];
    #pragma unroll
    for (int c = 0; c < 64; c++) xr[c] = xg[(size_t)c * NPOS];

    __shared__ float buf[32][65];

    float accs[8];
    #pragma unroll
    for (int rr = 0; rr < 8; rr++) {
        const int row = w * 8 + rr;                  // wave-uniform
        const float* wr = wsrc + row * 64;           // -> scalar loads
        float a0 = 0.f, a1 = 0.f, a2 = 0.f, a3 = 0.f;
        #pragma unroll
        for (int c = 0; c < 16; c++) {
            a0 += wr[c]      * xr[c];
            a1 += wr[c + 16] * xr[c + 16];
            a2 += wr[c + 32] * xr[c + 32];
            a3 += wr[c + 48] * xr[c + 48];
        }
        accs[rr] = (a0 + a1) + (a2 + a3);
    }

    if (p == 2) {   // V^T with per-tile slot permutation
        const int n   = n0 + lane;
        const int kk  = n & 127;
        const int g   = kk >> 4, qd = (kk >> 2) & 3, rr2 = kk & 3;
        const int slot = (g >> 1) * 32 + qd * 8 + (g & 1) * 4 + rr2;
        const size_t col = (size_t)(n >> 7) * 128 + slot;
        #pragma unroll
        for (int rr = 0; rr < 8; rr++)
            Vt[((size_t)b * 32 + w * 8 + rr) * NPOS + col] = (_Float16)accs[rr];
        return;
    }

    #pragma unroll
    for (int rr = 0; rr < 8; rr++) buf[w * 8 + rr][lane] = accs[rr];
    __syncthreads();

    const float scale = (p == 0) ? LOG2E : 1.f;
    _Float16* dst = (p == 0) ? Qh : Kh;
    const int pos = t >> 2, ic = t & 3;   // 8 consecutive inter-ch per thread
    f16x8 hv;
    #pragma unroll
    for (int j = 0; j < 8; j++)
        hv[j] = (_Float16)(buf[ic * 8 + j][pos] * scale);
    *(f16x8*)(dst + ((size_t)b * NPOS + n0 + pos) * 32 + ic * 8) = hv;
}

// ---------------------------------------------------------------------------
// Kernel 2: fp16 MFMA flash attention, split-K, register-P transposed
// dataflow, SINGLE-buffered LDS staging (18.9 KB -> ~7 blocks/CU so the
// whole 2000-block grid co-resides in one scheduling round; R10's dbuf at
// 38.4 KB forced two sequential rounds at 4 blocks/CU).  2 barriers/tile.
// Grid (N/64, SPLIT, B) = 2000 blocks, 256 thr = 4 waves x 16 queries.
//   S^T = K Q^T : A = K frag (LDS, wave-independent), B = Q frag (regs).
//     C-layout: lane(n16,quad) holds S^T[key=g*16+quad*4+r][q=n16].
//   softmax: lane-local max tree + shfl_xor(16,32); l cross-quad deferred.
//   O^T = V^T P^T : A = V frag (LDS, slot-permuted by proj), B = pb packed
//     from sc regs via v_cvt_pkrtz. P never touches LDS.
// ---------------------------------------------------------------------------
__global__ __launch_bounds__(256) void nlb_flash_kernel(
    const _Float16* __restrict__ Qh, const _Float16* __restrict__ Kh,
    const _Float16* __restrict__ Vt,
    _Float16* __restrict__ Opart, float2* __restrict__ ml)
{
    __shared__ __align__(16) _Float16 ks[128][40];   // 80B rows
    __shared__ __align__(16) _Float16 vs[32][136];   // 272B rows

    const int b     = blockIdx.z;
    const int split = blockIdx.y;
    const int t     = threadIdx.x;
    const int w     = t >> 6;
    const int lane  = t & 63;
    const int n16   = lane & 15;
    const int quad  = lane >> 4;
    const int q0    = blockIdx.x * 64 + w * 16;

    // Q fragment (B-operand of Q^T)
    const f16x8 qa = *(const f16x8*)(Qh + ((size_t)b * NPOS + q0 + n16) * 32 + quad * 8);

    const _Float16* KB = Kh + (size_t)b * NPOS * 32;
    const _Float16* VB = Vt + (size_t)b * 32 * NPOS;

    f32x4 o0 = (f32x4)0.f;              // dims quad*4+r      (query n16)
    f32x4 o1 = (f32x4)0.f;              // dims 16+quad*4+r
    float runm = -1e30f, lsum = 0.f;    // per-lane state for query n16

    // staging address components (two 16B chunks per thread for K and V)
    const int key0 = t >> 2, part = t & 3, key1 = key0 + 64;
    const int dim0 = t >> 4, kp   = t & 15, dim1 = dim0 + 16;

    const int kt0 = split * TPB;
    f16x8 kr0, kr1, vr0, vr1;
    {   // prologue fetch of first tile
        const int k0 = kt0 * 128;
        kr0 = *(const f16x8*)(KB + (size_t)(k0 + key0) * 32 + part * 8);
        kr1 = *(const f16x8*)(KB + (size_t)(k0 + key1) * 32 + part * 8);
        vr0 = *(const f16x8*)(VB + (size_t)dim0 * NPOS + k0 + kp * 8);
        vr1 = *(const f16x8*)(VB + (size_t)dim1 * NPOS + k0 + kp * 8);
    }

    for (int i = 0; i < TPB; i++) {
        if (i) __syncthreads();   // prior tile's LDS reads complete
        *(f16x8*)&ks[key0][part * 8] = kr0;
        *(f16x8*)&ks[key1][part * 8] = kr1;
        *(f16x8*)&vs[dim0][kp * 8]   = vr0;
        *(f16x8*)&vs[dim1][kp * 8]   = vr1;
        __syncthreads();

        if (i + 1 < TPB) {   // next-tile globals; in flight through compute
            const int k0n = (kt0 + i + 1) * 128;
            kr0 = *(const f16x8*)(KB + (size_t)(k0n + key0) * 32 + part * 8);
            kr1 = *(const f16x8*)(KB + (size_t)(k0n + key1) * 32 + part * 8);
            vr0 = *(const f16x8*)(VB + (size_t)dim0 * NPOS + k0n + kp * 8);
            vr1 = *(const f16x8*)(VB + (size_t)dim1 * NPOS + k0n + kp * 8);
        }

        // S^T = K Q^T
        f32x4 sc[8];
        #pragma unroll
        for (int g = 0; g < 8; g++) {
            f16x8 kf = *(const f16x8*)&ks[g * 16 + n16][quad * 8];
            f32x4 z = (f32x4)0.f;
            sc[g] = __builtin_amdgcn_mfma_f32_16x16x32_f16(kf, qa, z, 0, 0, 0);
        }

        // softmax over this query's 128 keys (lane owns 32; rest in n16+16k)
        float m = fmaxf(fmaxf(sc[0][0], sc[0][1]), fmaxf(sc[0][2], sc[0][3]));
        #pragma unroll
        for (int g = 1; g < 8; g++) {
            float mg = fmaxf(fmaxf(sc[g][0], sc[g][1]), fmaxf(sc[g][2], sc[g][3]));
            m = fmaxf(m, mg);
        }
        m = fmaxf(m, __shfl_xor(m, 16));
        m = fmaxf(m, __shfl_xor(m, 32));
        float nm = fmaxf(runm, m);
        float a  = __builtin_amdgcn_exp2f(runm - nm);
        runm = nm;
        float ls = 0.f;
        #pragma unroll
        for (int g = 0; g < 8; g++) {
            #pragma unroll
            for (int r = 0; r < 4; r++) {
                float p = __builtin_amdgcn_exp2f(sc[g][r] - nm);
                sc[g][r] = p;
                ls += p;
            }
        }
        lsum = lsum * a + ls;   // cross-quad sum deferred to epilogue
        o0 *= a;
        o1 *= a;

        // O^T += V^T P^T : pb[j] = P[key (kc*2+(j>>2))*16+quad*4+(j&3)]
        #pragma unroll
        for (int kc = 0; kc < 4; kc++) {
            union { f16x8 v; f16x2 h2[4]; } pb;
            pb.h2[0] = pkrtz(sc[kc * 2][0],     sc[kc * 2][1]);
            pb.h2[1] = pkrtz(sc[kc * 2][2],     sc[kc * 2][3]);
            pb.h2[2] = pkrtz(sc[kc * 2 + 1][0], sc[kc * 2 + 1][1]);
            pb.h2[3] = pkrtz(sc[kc * 2 + 1][2], sc[kc * 2 + 1][3]);
            f16x8 v0 = *(const f16x8*)&vs[n16][kc * 32 + quad * 8];
            f16x8 v1 = *(const f16x8*)&vs[16 + n16][kc * 32 + quad * 8];
            o0 = __builtin_amdgcn_mfma_f32_16x16x32_f16(v0, pb.v, o0, 0, 0, 0);
            o1 = __builtin_amdgcn_mfma_f32_16x16x32_f16(v1, pb.v, o1, 0, 0, 0);
        }
    }

    // epilogue: finish l across quads, normalize, store O^T + (m,l)
    lsum += __shfl_xor(lsum, 16);
    lsum += __shfl_xor(lsum, 32);
    float invl = 1.f / lsum;
    const size_t base = ((size_t)(b * SPLIT + split) * NPOS + q0 + n16) * 32;
    h4 h0, h1;
    #pragma unroll
    for (int r = 0; r < 4; r++) {
        h0[r] = (_Float16)(o0[r] * invl);
        h1[r] = (_Float16)(o1[r] * invl);
    }
    *(h4*)(Opart + base + quad * 4)      = h0;
    *(h4*)(Opart + base + 16 + quad * 4) = h1;
    if (quad == 0)
        ml[(size_t)(b * SPLIT + split) * NPOS + q0 + n16] = make_float2(runm, lsum);
}

// ---------------------------------------------------------------------------
// Kernel 3: flash-combine the SPLIT partials + W-projection + residual.
// Grid (N/32, B). Opart layout [b][split][q][32] -> coalesced 8B reads.
// ---------------------------------------------------------------------------
__global__ __launch_bounds__(256) void nlb_combine_kernel(
    const _Float16* __restrict__ Opart, const float2* __restrict__ ml,
    const float* __restrict__ w_w, const float* __restrict__ x,
    float* __restrict__ out)
{
    __shared__ float wf[64][33];
    __shared__ float wts[32][12];
    __shared__ float of[32][33];

    const int b  = blockIdx.y;
    const int q0 = blockIdx.x * 32;
    const int t  = threadIdx.x;

    for (int idx = t; idx < 2048; idx += 256) wf[idx >> 5][idx & 31] = w_w[idx];

    if (t < 32) {   // merge coefficients c_s = exp2(m_s-m*)*l_s / sum
        float2 v[SPLIT];
        float m = -1e30f;
        #pragma unroll
        for (int s = 0; s < SPLIT; s++) {
            v[s] = ml[(size_t)(b * SPLIT + s) * NPOS + q0 + t];
            m = fmaxf(m, v[s].x);
        }
        float suml = 0.f;
        #pragma unroll
        for (int s = 0; s < SPLIT; s++) {
            float wgt = __builtin_amdgcn_exp2f(v[s].x - m) * v[s].y;
            wts[t][s] = wgt;
            suml += wgt;
        }
        float inv = 1.f / suml;
        #pragma unroll
        for (int s = 0; s < SPLIT; s++) wts[t][s] *= inv;
    }
    __syncthreads();

    {   // merge partial O: thread -> (q = t>>3, dims dg*4..dg*4+3) COALESCED
        const int q = t >> 3, dg = t & 7;
        float a0 = 0.f, a1 = 0.f, a2 = 0.f, a3 = 0.f;
        #pragma unroll
        for (int s = 0; s < SPLIT; s++) {
            h4 hv = *(const h4*)(Opart +
                ((size_t)(b * SPLIT + s) * NPOS + q0 + q) * 32 + dg * 4);
            float c = wts[q][s];
            a0 += c * (float)hv[0]; a1 += c * (float)hv[1];
            a2 += c * (float)hv[2]; a3 += c * (float)hv[3];
        }
        of[q][dg * 4]     = a0; of[q][dg * 4 + 1] = a1;
        of[q][dg * 4 + 2] = a2; of[q][dg * 4 + 3] = a3;
    }
    __syncthreads();

    {   // y = W o + x: thread -> (query, 8 channels)
        const int q = t & 31, cg = t >> 5;
        const float* xb = x   + (size_t)b * CH * NPOS + q0 + q;
        float*       ob = out + (size_t)b * CH * NPOS + q0 + q;
        #pragma unroll
        for (int cc = 0; cc < 8; cc++) {
            int ch = cg * 8 + cc;
            float acc = 0.f;
            #pragma unroll
            for (int i = 0; i < 32; i++) acc += wf[ch][i] * of[q][i];
            ob[(size_t)ch * NPOS] = acc + xb[(size_t)ch * NPOS];
        }
    }
}

extern "C" void kernel_launch(void* const* d_in, const int* in_sizes, int n_in,
                              void* d_out, int out_size, void* d_ws, size_t ws_size,
                              hipStream_t stream) {
    const float* x    = (const float*)d_in[0];
    const float* g_w  = (const float*)d_in[1];
    const float* th_w = (const float*)d_in[2];
    const float* ph_w = (const float*)d_in[3];
    const float* w_w  = (const float*)d_in[4];
    float* out = (float*)d_out;

    const size_t SZ = (size_t)BATCH * NPOS * INTER;   // 409600 elements
    _Float16* Qh = (_Float16*)d_ws;
    _Float16* Kh = Qh + SZ;
    _Float16* Vt = Kh + SZ;
    _Float16* Opart = Vt + SZ;                         // [B][SPLIT][N][32]
    float2*   ml    = (float2*)(Opart + SZ * SPLIT);   // [B][SPLIT][N]

    nlb_proj_kernel<<<dim3(NPOS / 64, 3, BATCH), 256, 0, stream>>>(
        x, g_w, th_w, ph_w, Qh, Kh, Vt);
    nlb_flash_kernel<<<dim3(NPOS / 64, SPLIT, BATCH), 256, 0, stream>>>(
        Qh, Kh, Vt, Opart, ml);
    nlb_combine_kernel<<<dim3(NPOS / 32, BATCH), 256, 0, stream>>>(
        Opart, ml, w_w, x, out);
}